// Round 13
// baseline (232.616 us; speedup 1.0000x reference)
//
#include <hip/hip_runtime.h>
#include <hip/hip_fp16.h>
#include <math.h>

#define INC 128
#define F1 256
#define HEADS 4
#define NEG_SLOPE 0.2f

typedef _Float16 f16x8 __attribute__((ext_vector_type(8)));
typedef float f32x4 __attribute__((ext_vector_type(4)));

static __device__ __forceinline__ f16x8 f16x8_zero() {
    f16x8 v = {(_Float16)0, (_Float16)0, (_Float16)0, (_Float16)0,
               (_Float16)0, (_Float16)0, (_Float16)0, (_Float16)0};
    return v;
}

// ---------------- prep: W1T + w1s/w1d projections + hist/rank ----------------
__global__ __launch_bounds__(256) void prep_kernel(
    const float* __restrict__ W1, _Float16* __restrict__ W1T,
    const float* __restrict__ att_s, const float* __restrict__ att_d,
    float* __restrict__ w1s, float* __restrict__ w1d,
    const int* __restrict__ ei, int* __restrict__ deg, int* __restrict__ rank,
    int E, int Etot, int nw1t)
{
    int b = blockIdx.x;
    if (b < nw1t) {
        int i = b * 256 + threadIdx.x;   // 32768 elements
        int k = i >> 8;
        int c = i & 255;
        W1T[c * 128 + k] = (_Float16)W1[i];
    } else if (b < nw1t + ((Etot + 255) >> 8)) {
        int e = (b - nw1t) * 256 + threadIdx.x;
        if (e < Etot) {
            int d = (e < E) ? ei[E + e] : (e - E);
            rank[e] = atomicAdd(&deg[d], 1);
        }
    } else {
        // w1s[h][k] = sum_c W1[k][h*64+c]*att_s[h*64+c]; same for w1d
        #pragma unroll
        for (int rep = 0; rep < 2; ++rep) {
            int idx = threadIdx.x + rep * 256;   // 512 outputs
            int h = idx >> 7;
            int k = idx & 127;
            float ss = 0.f, sd = 0.f;
            for (int c = 0; c < 64; ++c) {
                float w = W1[k * F1 + h * 64 + c];
                ss += w * att_s[h * 64 + c];
                sd += w * att_d[h * 64 + c];
            }
            w1s[h * 128 + k] = ss;
            w1d[h * 128 + k] = sd;
        }
    }
}

// ---------------- scan1 ----------------
__global__ __launch_bounds__(256) void scan1_kernel(
    const int* __restrict__ deg, int* __restrict__ incl,
    int* __restrict__ bsum, int N)
{
    __shared__ int tmp[256];
    int i = blockIdx.x * 256 + threadIdx.x;
    int v = (i < N) ? deg[i] : 0;
    tmp[threadIdx.x] = v;
    __syncthreads();
    for (int o = 1; o < 256; o <<= 1) {
        int add = (threadIdx.x >= o) ? tmp[threadIdx.x - o] : 0;
        __syncthreads();
        tmp[threadIdx.x] += add;
        __syncthreads();
    }
    if (i < N) incl[i] = tmp[threadIdx.x];
    if (threadIdx.x == 255) bsum[blockIdx.x] = tmp[255];
}

// ---------------- scan3 ----------------
__global__ __launch_bounds__(256) void scan3_kernel(
    const int* __restrict__ deg, const int* __restrict__ incl,
    const int* __restrict__ bsum, int* __restrict__ off,
    int N, int Etot, int nb)
{
    __shared__ int tmp[256];
    const int bid = blockIdx.x;
    const int t = threadIdx.x;
    tmp[t] = (t < bid && t < nb) ? bsum[t] : 0;
    __syncthreads();
    #pragma unroll
    for (int o = 128; o > 0; o >>= 1) {
        if (t < o) tmp[t] += tmp[t + o];
        __syncthreads();
    }
    int pre = tmp[0];
    int i = bid * 256 + t;
    if (i < N) {
        off[i] = incl[i] - deg[i] + pre;
    } else if (i == N) {
        off[N] = Etot;
    }
}

// ---------------- mid: fill (atomic-free) || logits a_src/a_dst + x->fp16 cast ----------------
__global__ __launch_bounds__(256) void mid_kernel(
    const int* __restrict__ ei, const int* __restrict__ rank,
    const int* __restrict__ off, int* __restrict__ esrc,
    const float* __restrict__ x, const float* __restrict__ w1s,
    const float* __restrict__ w1d, float* __restrict__ a_src,
    float* __restrict__ a_dst, unsigned* __restrict__ x_h,
    int N, int E, int Etot, int egrid)
{
    if ((int)blockIdx.x < egrid) {
        int e = blockIdx.x * 256 + threadIdx.x;
        if (e < Etot) {
            int s, d;
            if (e < E) { s = ei[e]; d = ei[E + e]; }
            else       { s = d = e - E; }
            esrc[off[d] + rank[e]] = s;
        }
        return;
    }
    int wave = threadIdx.x >> 6;
    int lane = threadIdx.x & 63;
    int n = (blockIdx.x - egrid) * 4 + wave;
    if (n >= N) return;
    float2 xv = *(const float2*)&x[(size_t)n * INC + lane * 2];
    __half2 xh = __floats2half2_rn(xv.x, xv.y);
    x_h[(size_t)n * 64 + lane] = *(unsigned*)&xh;
    float ps[4], pd[4];
    #pragma unroll
    for (int h = 0; h < 4; ++h) {
        float2 ws = *(const float2*)&w1s[h * 128 + lane * 2];
        float2 wd = *(const float2*)&w1d[h * 128 + lane * 2];
        ps[h] = xv.x * ws.x + xv.y * ws.y;
        pd[h] = xv.x * wd.x + xv.y * wd.y;
    }
    #pragma unroll
    for (int o = 32; o > 0; o >>= 1) {
        #pragma unroll
        for (int h = 0; h < 4; ++h) {
            ps[h] += __shfl_xor(ps[h], o);
            pd[h] += __shfl_xor(pd[h], o);
        }
    }
    if (lane == 0) {
        *(float4*)&a_src[n * HEADS] = make_float4(ps[0], ps[1], ps[2], ps[3]);
        *(float4*)&a_dst[n * HEADS] = make_float4(pd[0], pd[1], pd[2], pd[3]);
    }
}

// ---------------- aggx: per-head aggregate of x_fp16 + fused blockdiag GEMM -> z ----------------
// One WAVE per node (gather phase); then wave w = head w for the 4-node MFMA epilogue.
__global__ __launch_bounds__(256) void aggx_kernel(
    const unsigned* __restrict__ x_h, const float* __restrict__ a_src,
    const float* __restrict__ a_dst, const int* __restrict__ off,
    const int* __restrict__ esrc, const _Float16* __restrict__ W1T,
    const float* __restrict__ bias1, const float* __restrict__ W2,
    float* __restrict__ z, int N)
{
    __shared__ unsigned lalh[4][64][4];     // [wave][edge][head] half2{a,a}
    __shared__ int lsrc_s[4][64];
    __shared__ __align__(16) _Float16 aggl[4][4][144];  // [head][node][k], padded
    __shared__ float zpart[4][4];           // [head][node]

    const int wave = threadIdx.x >> 6;
    const int lane = threadIdx.x & 63;
    const int n = blockIdx.x * 4 + wave;
    const bool nvalid = n < N;

    int beg = 0, end = 0;
    if (nvalid) { beg = off[n]; end = off[n + 1]; }
    const int deg = end - beg;
    const float4* a_src4 = (const float4*)a_src;
    float ad[4] = {0.f, 0.f, 0.f, 0.f};
    if (nvalid) {
        float4 ad4 = *(const float4*)&a_dst[n * HEADS];
        ad[0] = ad4.x; ad[1] = ad4.y; ad[2] = ad4.z; ad[3] = ad4.w;
    }

    __half2 acc[4];
    #pragma unroll
    for (int h = 0; h < 4; ++h) acc[h] = __float2half2_rn(0.f);

    #define GATHER(CNT)                                                          \
    {                                                                            \
        int j = 0;                                                               \
        for (; j + 4 <= (CNT); j += 4) {                                         \
            int s0 = lsrc_s[wave][j + 0];                                        \
            int s1 = lsrc_s[wave][j + 1];                                        \
            int s2 = lsrc_s[wave][j + 2];                                        \
            int s3 = lsrc_s[wave][j + 3];                                        \
            unsigned v0 = x_h[(size_t)s0 * 64 + lane];                           \
            unsigned v1 = x_h[(size_t)s1 * 64 + lane];                           \
            unsigned v2 = x_h[(size_t)s2 * 64 + lane];                           \
            unsigned v3 = x_h[(size_t)s3 * 64 + lane];                           \
            uint4 a0 = *(uint4*)&lalh[wave][j + 0][0];                           \
            uint4 a1 = *(uint4*)&lalh[wave][j + 1][0];                           \
            uint4 a2 = *(uint4*)&lalh[wave][j + 2][0];                           \
            uint4 a3 = *(uint4*)&lalh[wave][j + 3][0];                           \
            __half2 h0 = *(__half2*)&v0, h1v = *(__half2*)&v1;                   \
            __half2 h2v = *(__half2*)&v2, h3 = *(__half2*)&v3;                   \
            acc[0] = __hfma2(*(__half2*)&a0.x, h0, acc[0]);                      \
            acc[1] = __hfma2(*(__half2*)&a0.y, h0, acc[1]);                      \
            acc[2] = __hfma2(*(__half2*)&a0.z, h0, acc[2]);                      \
            acc[3] = __hfma2(*(__half2*)&a0.w, h0, acc[3]);                      \
            acc[0] = __hfma2(*(__half2*)&a1.x, h1v, acc[0]);                     \
            acc[1] = __hfma2(*(__half2*)&a1.y, h1v, acc[1]);                     \
            acc[2] = __hfma2(*(__half2*)&a1.z, h1v, acc[2]);                     \
            acc[3] = __hfma2(*(__half2*)&a1.w, h1v, acc[3]);                     \
            acc[0] = __hfma2(*(__half2*)&a2.x, h2v, acc[0]);                     \
            acc[1] = __hfma2(*(__half2*)&a2.y, h2v, acc[1]);                     \
            acc[2] = __hfma2(*(__half2*)&a2.z, h2v, acc[2]);                     \
            acc[3] = __hfma2(*(__half2*)&a2.w, h2v, acc[3]);                     \
            acc[0] = __hfma2(*(__half2*)&a3.x, h3, acc[0]);                      \
            acc[1] = __hfma2(*(__half2*)&a3.y, h3, acc[1]);                      \
            acc[2] = __hfma2(*(__half2*)&a3.z, h3, acc[2]);                      \
            acc[3] = __hfma2(*(__half2*)&a3.w, h3, acc[3]);                      \
        }                                                                        \
        for (; j < (CNT); ++j) {                                                 \
            int s0 = lsrc_s[wave][j];                                            \
            unsigned v0 = x_h[(size_t)s0 * 64 + lane];                           \
            uint4 a0 = *(uint4*)&lalh[wave][j][0];                               \
            __half2 h0 = *(__half2*)&v0;                                         \
            acc[0] = __hfma2(*(__half2*)&a0.x, h0, acc[0]);                      \
            acc[1] = __hfma2(*(__half2*)&a0.y, h0, acc[1]);                      \
            acc[2] = __hfma2(*(__half2*)&a0.z, h0, acc[2]);                      \
            acc[3] = __hfma2(*(__half2*)&a0.w, h0, acc[3]);                      \
        }                                                                        \
    }

    if (deg > 0 && deg <= 64) {
        int i = beg + lane;
        bool valid = i < end;
        int sN = esrc[valid ? i : beg];
        float4 a4 = a_src4[sN];
        float av[4] = {a4.x, a4.y, a4.z, a4.w};
        float ev[4];
        #pragma unroll
        for (int h = 0; h < 4; ++h) {
            float e = av[h] + ad[h];
            e = e > 0.f ? e : NEG_SLOPE * e;
            ev[h] = valid ? e : -1e30f;
        }
        float m[4] = {ev[0], ev[1], ev[2], ev[3]};
        #pragma unroll
        for (int o = 32; o > 0; o >>= 1) {
            #pragma unroll
            for (int h = 0; h < 4; ++h) m[h] = fmaxf(m[h], __shfl_xor(m[h], o));
        }
        float at[4];
        #pragma unroll
        for (int h = 0; h < 4; ++h) at[h] = valid ? __expf(ev[h] - m[h]) : 0.f;
        float s[4] = {at[0], at[1], at[2], at[3]};
        #pragma unroll
        for (int o = 32; o > 0; o >>= 1) {
            #pragma unroll
            for (int h = 0; h < 4; ++h) s[h] += __shfl_xor(s[h], o);
        }
        uint4 pack;
        __half2 t0 = __float2half2_rn(at[0] / s[0]);
        __half2 t1 = __float2half2_rn(at[1] / s[1]);
        __half2 t2 = __float2half2_rn(at[2] / s[2]);
        __half2 t3 = __float2half2_rn(at[3] / s[3]);
        pack.x = *(unsigned*)&t0; pack.y = *(unsigned*)&t1;
        pack.z = *(unsigned*)&t2; pack.w = *(unsigned*)&t3;
        *(uint4*)&lalh[wave][lane][0] = pack;
        lsrc_s[wave][lane] = sN;

        GATHER(deg);
    } else if (deg > 64) {
        float m[4] = {-1e30f, -1e30f, -1e30f, -1e30f};
        float s[4] = {0.f, 0.f, 0.f, 0.f};
        for (int i = beg + lane; i < end; i += 64) {
            int sN = esrc[i];
            float4 a4 = a_src4[sN];
            float av[4] = {a4.x, a4.y, a4.z, a4.w};
            #pragma unroll
            for (int h = 0; h < 4; ++h) {
                float e = av[h] + ad[h];
                e = e > 0.f ? e : NEG_SLOPE * e;
                float nm = fmaxf(m[h], e);
                s[h] = s[h] * __expf(m[h] - nm) + __expf(e - nm);
                m[h] = nm;
            }
        }
        #pragma unroll
        for (int o = 32; o > 0; o >>= 1) {
            #pragma unroll
            for (int h = 0; h < 4; ++h) {
                float om = __shfl_xor(m[h], o);
                float os = __shfl_xor(s[h], o);
                float nm = fmaxf(m[h], om);
                s[h] = s[h] * __expf(m[h] - nm) + os * __expf(om - nm);
                m[h] = nm;
            }
        }
        float inv[4];
        #pragma unroll
        for (int h = 0; h < 4; ++h) inv[h] = 1.f / s[h];

        for (int c0 = beg; c0 < end; c0 += 64) {
            int i = c0 + lane;
            if (i < end) {
                int sN = esrc[i];
                float4 a4 = a_src4[sN];
                float av[4] = {a4.x, a4.y, a4.z, a4.w};
                uint4 pack;
                #pragma unroll
                for (int h = 0; h < 4; ++h) {
                    float e = av[h] + ad[h];
                    e = e > 0.f ? e : NEG_SLOPE * e;
                    __half2 a2h = __float2half2_rn(__expf(e - m[h]) * inv[h]);
                    ((unsigned*)&pack)[h] = *(unsigned*)&a2h;
                }
                *(uint4*)&lalh[wave][lane][0] = pack;
                lsrc_s[wave][lane] = sN;
            }
            int cend = end - c0;
            if (cend > 64) cend = 64;
            GATHER(cend);
        }
    }
    #undef GATHER

    // stage agg rows to LDS: aggl[head][node][k]
    #pragma unroll
    for (int h = 0; h < 4; ++h)
        *(unsigned*)&aggl[h][wave][lane * 2] = *(unsigned*)&acc[h];
    __syncthreads();

    // fused block-diag GEMM: wave w = head w; cols w*64..w*64+63; nodes 0..3 as A rows
    const int q = lane >> 4;
    const int c16 = lane & 15;
    f16x8 af[4];
    #pragma unroll
    for (int kc = 0; kc < 4; ++kc) {
        af[kc] = (c16 < 4) ? *(const f16x8*)&aggl[wave][c16][kc * 32 + q * 8]
                           : f16x8_zero();
    }
    float pz[4] = {};
    #pragma unroll
    for (int t = 0; t < 4; ++t) {
        int col = wave * 64 + t * 16 + c16;
        f32x4 dacc = {0.f, 0.f, 0.f, 0.f};
        #pragma unroll
        for (int kc = 0; kc < 4; ++kc) {
            f16x8 b = *(const f16x8*)&W1T[(size_t)col * 128 + kc * 32 + q * 8];
            dacc = __builtin_amdgcn_mfma_f32_16x16x32_f16(af[kc], b, dacc, 0, 0, 0);
        }
        float bv = bias1[col];
        float wv = W2[col];
        #pragma unroll
        for (int reg = 0; reg < 4; ++reg) {
            float o = dacc[reg] + bv;
            o = o > 0.f ? o : __expf(o) - 1.f;
            pz[reg] = fmaf(o, wv, pz[reg]);
        }
    }
    // valid D rows (nodes 0-3) live in q==0 lanes; reduce over c16 within that group
    #pragma unroll
    for (int o = 8; o > 0; o >>= 1) {
        #pragma unroll
        for (int reg = 0; reg < 4; ++reg) pz[reg] += __shfl_xor(pz[reg], o);
    }
    if (lane == 0) {
        #pragma unroll
        for (int reg = 0; reg < 4; ++reg) zpart[wave][reg] = pz[reg];
    }
    __syncthreads();
    if (threadIdx.x < 4) {
        int row = blockIdx.x * 4 + threadIdx.x;
        if (row < N)
            z[row] = zpart[0][threadIdx.x] + zpart[1][threadIdx.x] +
                     zpart[2][threadIdx.x] + zpart[3][threadIdx.x];
    }
}

// ---------------- Layer-2 aggregation: one wave per node ----------------
__global__ __launch_bounds__(256) void agg2_kernel(
    const float* __restrict__ z, const int* __restrict__ off,
    const int* __restrict__ esrc, const float* __restrict__ att_s2,
    const float* __restrict__ att_d2, const float* __restrict__ bias2,
    float* __restrict__ out, int N)
{
    int wave = threadIdx.x >> 6;
    int lane = threadIdx.x & 63;
    int n = blockIdx.x * 4 + wave;
    if (n >= N) return;
    float as2 = att_s2[0], ad2 = att_d2[0];
    int beg = off[n], end = off[n + 1];
    int deg = end - beg;
    float dstterm = z[n] * ad2;

    if (deg <= 64) {
        int i = beg + lane;
        bool valid = i < end;
        int sN = esrc[valid ? i : beg];
        float zv = z[sN];
        float e = zv * as2 + dstterm;
        e = e > 0.f ? e : NEG_SLOPE * e;
        float ev = valid ? e : -1e30f;
        float m = ev;
        #pragma unroll
        for (int o = 32; o > 0; o >>= 1) m = fmaxf(m, __shfl_xor(m, o));
        float at = valid ? __expf(ev - m) : 0.f;
        float s = at, wv = at * zv;
        #pragma unroll
        for (int o = 32; o > 0; o >>= 1) {
            s += __shfl_xor(s, o);
            wv += __shfl_xor(wv, o);
        }
        if (lane == 0) out[n] = wv / s + bias2[0];
    } else {
        float m = -1e30f, s = 0.f, wv = 0.f;
        for (int i = beg + lane; i < end; i += 64) {
            int sN = esrc[i];
            float zv = z[sN];
            float e = zv * as2 + dstterm;
            e = e > 0.f ? e : NEG_SLOPE * e;
            float nm = fmaxf(m, e);
            float c0 = __expf(m - nm), c1 = __expf(e - nm);
            s = s * c0 + c1;
            wv = wv * c0 + c1 * zv;
            m = nm;
        }
        #pragma unroll
        for (int o = 32; o > 0; o >>= 1) {
            float om = __shfl_xor(m, o), os = __shfl_xor(s, o), ow = __shfl_xor(wv, o);
            float nm = fmaxf(m, om);
            float c0 = __expf(m - nm), c1 = __expf(om - nm);
            s = s * c0 + os * c1;
            wv = wv * c0 + ow * c1;
            m = nm;
        }
        if (lane == 0) out[n] = wv / s + bias2[0];
    }
}

// ---------------- launch ----------------
extern "C" void kernel_launch(void* const* d_in, const int* in_sizes, int n_in,
                              void* d_out, int out_size, void* d_ws, size_t ws_size,
                              hipStream_t stream)
{
    const float* x        = (const float*)d_in[0];
    const int*   ei       = (const int*)d_in[1];
    const float* W1       = (const float*)d_in[2];
    const float* att_src1 = (const float*)d_in[3];
    const float* att_dst1 = (const float*)d_in[4];
    const float* bias1    = (const float*)d_in[5];
    const float* W2       = (const float*)d_in[6];
    const float* att_src2 = (const float*)d_in[7];
    const float* att_dst2 = (const float*)d_in[8];
    const float* bias2    = (const float*)d_in[9];
    float* out = (float*)d_out;

    int N = in_sizes[0] / INC;
    int E = in_sizes[1] / 2;
    int Etot = E + N;

    char* p = (char*)d_ws;
    auto alloc = [&](size_t bytes) {
        void* r = (void*)p;
        p += (bytes + 255) & ~(size_t)255;
        return r;
    };
    unsigned* x_h   = (unsigned*)alloc((size_t)N * 64 * 4);        // fp16 x, 12.8 MB
    _Float16* W1T   = (_Float16*)alloc((size_t)INC * F1 * 2);
    float* w1s    = (float*)alloc(4 * 128 * 4);
    float* w1d    = (float*)alloc(4 * 128 * 4);
    float* a_src1 = (float*)alloc((size_t)N * HEADS * 4);
    float* a_dst1 = (float*)alloc((size_t)N * HEADS * 4);
    float* z      = (float*)alloc((size_t)N * 4);
    int* deg    = (int*)alloc((size_t)N * 4);
    int* incl   = (int*)alloc((size_t)N * 4);
    int* off    = (int*)alloc((size_t)(N + 1) * 4);
    int* rank   = (int*)alloc((size_t)Etot * 4);
    int* bsum   = (int*)alloc(1024);
    int* esrc   = (int*)alloc((size_t)Etot * 4);

    hipMemsetAsync(deg, 0, (size_t)N * 4, stream);

    int nw1t = INC * F1 / 256;              // 128
    int egrid = (Etot + 255) / 256;
    prep_kernel<<<nw1t + egrid + 1, 256, 0, stream>>>(
        W1, W1T, att_src1, att_dst1, w1s, w1d, ei, deg, rank, E, Etot, nw1t);

    int nb = (N + 255) / 256;
    scan1_kernel<<<nb, 256, 0, stream>>>(deg, incl, bsum, N);

    int nb1 = (N + 1 + 255) / 256;
    scan3_kernel<<<nb1, 256, 0, stream>>>(deg, incl, bsum, off, N, Etot, nb);

    int nlog = (N + 3) / 4;
    mid_kernel<<<egrid + nlog, 256, 0, stream>>>(
        ei, rank, off, esrc, x, w1s, w1d, a_src1, a_dst1, x_h, N, E, Etot, egrid);

    int ngrid1 = (N + 3) / 4;
    aggx_kernel<<<ngrid1, 256, 0, stream>>>(
        x_h, a_src1, a_dst1, off, esrc, W1T, bias1, W2, z, N);

    int ngrid2 = (N + 3) / 4;
    agg2_kernel<<<ngrid2, 256, 0, stream>>>(z, off, esrc, att_src2, att_dst2, bias2, out, N);
}

// Round 14
// 188.680 us; speedup vs baseline: 1.2329x; 1.2329x over previous
//
#include <hip/hip_runtime.h>
#include <hip/hip_fp16.h>
#include <math.h>

#define INC 128
#define F1 256
#define HEADS 4
#define NEG_SLOPE 0.2f

typedef _Float16 f16x8 __attribute__((ext_vector_type(8)));
typedef float f32x4 __attribute__((ext_vector_type(4)));

// ---------------- prep: W1T + w1s/w1d projections + hist/rank ----------------
__global__ __launch_bounds__(256) void prep_kernel(
    const float* __restrict__ W1, _Float16* __restrict__ W1T,
    const float* __restrict__ att_s, const float* __restrict__ att_d,
    float* __restrict__ w1s, float* __restrict__ w1d,
    const int* __restrict__ ei, int* __restrict__ deg, int* __restrict__ rank,
    int E, int Etot, int nw1t)
{
    int b = blockIdx.x;
    if (b < nw1t) {
        int i = b * 256 + threadIdx.x;   // 32768 elements
        int k = i >> 8;
        int c = i & 255;
        W1T[c * 128 + k] = (_Float16)W1[i];
    } else if (b < nw1t + ((Etot + 255) >> 8)) {
        int e = (b - nw1t) * 256 + threadIdx.x;
        if (e < Etot) {
            int d = (e < E) ? ei[E + e] : (e - E);
            rank[e] = atomicAdd(&deg[d], 1);
        }
    } else {
        // w1s[h][k] = sum_c W1[k][h*64+c]*att_s[h*64+c]; same for w1d
        #pragma unroll
        for (int rep = 0; rep < 2; ++rep) {
            int idx = threadIdx.x + rep * 256;   // 512 outputs
            int h = idx >> 7;
            int k = idx & 127;
            float ss = 0.f, sd = 0.f;
            for (int c = 0; c < 64; ++c) {
                float w = W1[k * F1 + h * 64 + c];
                ss += w * att_s[h * 64 + c];
                sd += w * att_d[h * 64 + c];
            }
            w1s[h * 128 + k] = ss;
            w1d[h * 128 + k] = sd;
        }
    }
}

// ---------------- scan1 ----------------
__global__ __launch_bounds__(256) void scan1_kernel(
    const int* __restrict__ deg, int* __restrict__ incl,
    int* __restrict__ bsum, int N)
{
    __shared__ int tmp[256];
    int i = blockIdx.x * 256 + threadIdx.x;
    int v = (i < N) ? deg[i] : 0;
    tmp[threadIdx.x] = v;
    __syncthreads();
    for (int o = 1; o < 256; o <<= 1) {
        int add = (threadIdx.x >= o) ? tmp[threadIdx.x - o] : 0;
        __syncthreads();
        tmp[threadIdx.x] += add;
        __syncthreads();
    }
    if (i < N) incl[i] = tmp[threadIdx.x];
    if (threadIdx.x == 255) bsum[blockIdx.x] = tmp[255];
}

// ---------------- scan3 ----------------
__global__ __launch_bounds__(256) void scan3_kernel(
    const int* __restrict__ deg, const int* __restrict__ incl,
    const int* __restrict__ bsum, int* __restrict__ off,
    int N, int Etot, int nb)
{
    __shared__ int tmp[256];
    const int bid = blockIdx.x;
    const int t = threadIdx.x;
    tmp[t] = (t < bid && t < nb) ? bsum[t] : 0;
    __syncthreads();
    #pragma unroll
    for (int o = 128; o > 0; o >>= 1) {
        if (t < o) tmp[t] += tmp[t + o];
        __syncthreads();
    }
    int pre = tmp[0];
    int i = bid * 256 + t;
    if (i < N) {
        off[i] = incl[i] - deg[i] + pre;
    } else if (i == N) {
        off[N] = Etot;
    }
}

// ---------------- mid: fill (atomic-free) || logits a_src/a_dst + x->fp16 cast ----------------
__global__ __launch_bounds__(256) void mid_kernel(
    const int* __restrict__ ei, const int* __restrict__ rank,
    const int* __restrict__ off, int* __restrict__ esrc,
    const float* __restrict__ x, const float* __restrict__ w1s,
    const float* __restrict__ w1d, float* __restrict__ a_src,
    float* __restrict__ a_dst, unsigned* __restrict__ x_h,
    int N, int E, int Etot, int egrid)
{
    if ((int)blockIdx.x < egrid) {
        int e = blockIdx.x * 256 + threadIdx.x;
        if (e < Etot) {
            int s, d;
            if (e < E) { s = ei[e]; d = ei[E + e]; }
            else       { s = d = e - E; }
            esrc[off[d] + rank[e]] = s;
        }
        return;
    }
    int wave = threadIdx.x >> 6;
    int lane = threadIdx.x & 63;
    int n = (blockIdx.x - egrid) * 4 + wave;
    if (n >= N) return;
    float2 xv = *(const float2*)&x[(size_t)n * INC + lane * 2];
    __half2 xh = __floats2half2_rn(xv.x, xv.y);
    x_h[(size_t)n * 64 + lane] = *(unsigned*)&xh;
    float ps[4], pd[4];
    #pragma unroll
    for (int h = 0; h < 4; ++h) {
        float2 ws = *(const float2*)&w1s[h * 128 + lane * 2];
        float2 wd = *(const float2*)&w1d[h * 128 + lane * 2];
        ps[h] = xv.x * ws.x + xv.y * ws.y;
        pd[h] = xv.x * wd.x + xv.y * wd.y;
    }
    #pragma unroll
    for (int o = 32; o > 0; o >>= 1) {
        #pragma unroll
        for (int h = 0; h < 4; ++h) {
            ps[h] += __shfl_xor(ps[h], o);
            pd[h] += __shfl_xor(pd[h], o);
        }
    }
    if (lane == 0) {
        *(float4*)&a_src[n * HEADS] = make_float4(ps[0], ps[1], ps[2], ps[3]);
        *(float4*)&a_dst[n * HEADS] = make_float4(pd[0], pd[1], pd[2], pd[3]);
    }
}

// ---------------- aggx: 32 nodes/block (8 waves); gather x_fp16 per-head, then
// round-12-gemm2-style fused block-diag MFMA epilogue -> z. No agg round-trip. ----------------
__global__ __launch_bounds__(512) void aggx_kernel(
    const unsigned* __restrict__ x_h, const float* __restrict__ a_src,
    const float* __restrict__ a_dst, const int* __restrict__ off,
    const int* __restrict__ esrc, const _Float16* __restrict__ W1T,
    const float* __restrict__ bias1, const float* __restrict__ W2,
    float* __restrict__ z, int N)
{
    __shared__ unsigned lalh[8][64][4];                 // [wave][edge][head] half2{a,a}
    __shared__ int lsrc_s[8][64];
    __shared__ __align__(16) _Float16 aggl[32][520];    // [local node][512+pad]
    __shared__ float zpart[4][32];                      // [col-group][local node]

    const int wave = threadIdx.x >> 6;   // 0..7
    const int lane = threadIdx.x & 63;
    const int row0 = blockIdx.x * 32;
    const float4* a_src4 = (const float4*)a_src;

    #define GATHER(CNT)                                                          \
    {                                                                            \
        int j = 0;                                                               \
        for (; j + 4 <= (CNT); j += 4) {                                         \
            int s0 = lsrc_s[wave][j + 0];                                        \
            int s1 = lsrc_s[wave][j + 1];                                        \
            int s2 = lsrc_s[wave][j + 2];                                        \
            int s3 = lsrc_s[wave][j + 3];                                        \
            unsigned v0 = x_h[(size_t)s0 * 64 + lane];                           \
            unsigned v1 = x_h[(size_t)s1 * 64 + lane];                           \
            unsigned v2 = x_h[(size_t)s2 * 64 + lane];                           \
            unsigned v3 = x_h[(size_t)s3 * 64 + lane];                           \
            uint4 a0 = *(uint4*)&lalh[wave][j + 0][0];                           \
            uint4 a1 = *(uint4*)&lalh[wave][j + 1][0];                           \
            uint4 a2 = *(uint4*)&lalh[wave][j + 2][0];                           \
            uint4 a3 = *(uint4*)&lalh[wave][j + 3][0];                           \
            __half2 h0 = *(__half2*)&v0, h1v = *(__half2*)&v1;                   \
            __half2 h2v = *(__half2*)&v2, h3 = *(__half2*)&v3;                   \
            acc[0] = __hfma2(*(__half2*)&a0.x, h0, acc[0]);                      \
            acc[1] = __hfma2(*(__half2*)&a0.y, h0, acc[1]);                      \
            acc[2] = __hfma2(*(__half2*)&a0.z, h0, acc[2]);                      \
            acc[3] = __hfma2(*(__half2*)&a0.w, h0, acc[3]);                      \
            acc[0] = __hfma2(*(__half2*)&a1.x, h1v, acc[0]);                     \
            acc[1] = __hfma2(*(__half2*)&a1.y, h1v, acc[1]);                     \
            acc[2] = __hfma2(*(__half2*)&a1.z, h1v, acc[2]);                     \
            acc[3] = __hfma2(*(__half2*)&a1.w, h1v, acc[3]);                     \
            acc[0] = __hfma2(*(__half2*)&a2.x, h2v, acc[0]);                     \
            acc[1] = __hfma2(*(__half2*)&a2.y, h2v, acc[1]);                     \
            acc[2] = __hfma2(*(__half2*)&a2.z, h2v, acc[2]);                     \
            acc[3] = __hfma2(*(__half2*)&a2.w, h2v, acc[3]);                     \
            acc[0] = __hfma2(*(__half2*)&a3.x, h3, acc[0]);                      \
            acc[1] = __hfma2(*(__half2*)&a3.y, h3, acc[1]);                      \
            acc[2] = __hfma2(*(__half2*)&a3.z, h3, acc[2]);                      \
            acc[3] = __hfma2(*(__half2*)&a3.w, h3, acc[3]);                      \
        }                                                                        \
        for (; j < (CNT); ++j) {                                                 \
            int s0 = lsrc_s[wave][j];                                            \
            unsigned v0 = x_h[(size_t)s0 * 64 + lane];                           \
            uint4 a0 = *(uint4*)&lalh[wave][j][0];                               \
            __half2 h0 = *(__half2*)&v0;                                         \
            acc[0] = __hfma2(*(__half2*)&a0.x, h0, acc[0]);                      \
            acc[1] = __hfma2(*(__half2*)&a0.y, h0, acc[1]);                      \
            acc[2] = __hfma2(*(__half2*)&a0.z, h0, acc[2]);                      \
            acc[3] = __hfma2(*(__half2*)&a0.w, h0, acc[3]);                      \
        }                                                                        \
    }

    // ---- gather phase: each wave handles 4 nodes sequentially ----
    for (int it = 0; it < 4; ++it) {
        const int ln = wave * 4 + it;     // local node 0..31
        const int n = row0 + ln;

        __half2 acc[4];
        #pragma unroll
        for (int h = 0; h < 4; ++h) acc[h] = __float2half2_rn(0.f);

        if (n < N) {
            const int beg = off[n], end = off[n + 1];
            const int deg = end - beg;
            float4 ad4 = *(const float4*)&a_dst[n * HEADS];
            float ad[4] = {ad4.x, ad4.y, ad4.z, ad4.w};

            if (deg > 0 && deg <= 64) {
                int i = beg + lane;
                bool valid = i < end;
                int sN = esrc[valid ? i : beg];
                float4 a4 = a_src4[sN];
                float av[4] = {a4.x, a4.y, a4.z, a4.w};
                float ev[4];
                #pragma unroll
                for (int h = 0; h < 4; ++h) {
                    float e = av[h] + ad[h];
                    e = e > 0.f ? e : NEG_SLOPE * e;
                    ev[h] = valid ? e : -1e30f;
                }
                float m[4] = {ev[0], ev[1], ev[2], ev[3]};
                #pragma unroll
                for (int o = 32; o > 0; o >>= 1) {
                    #pragma unroll
                    for (int h = 0; h < 4; ++h) m[h] = fmaxf(m[h], __shfl_xor(m[h], o));
                }
                float at[4];
                #pragma unroll
                for (int h = 0; h < 4; ++h) at[h] = valid ? __expf(ev[h] - m[h]) : 0.f;
                float s[4] = {at[0], at[1], at[2], at[3]};
                #pragma unroll
                for (int o = 32; o > 0; o >>= 1) {
                    #pragma unroll
                    for (int h = 0; h < 4; ++h) s[h] += __shfl_xor(s[h], o);
                }
                uint4 pack;
                __half2 t0 = __float2half2_rn(at[0] / s[0]);
                __half2 t1 = __float2half2_rn(at[1] / s[1]);
                __half2 t2 = __float2half2_rn(at[2] / s[2]);
                __half2 t3 = __float2half2_rn(at[3] / s[3]);
                pack.x = *(unsigned*)&t0; pack.y = *(unsigned*)&t1;
                pack.z = *(unsigned*)&t2; pack.w = *(unsigned*)&t3;
                *(uint4*)&lalh[wave][lane][0] = pack;
                lsrc_s[wave][lane] = sN;

                GATHER(deg);
            } else if (deg > 64) {
                float m[4] = {-1e30f, -1e30f, -1e30f, -1e30f};
                float s[4] = {0.f, 0.f, 0.f, 0.f};
                for (int i = beg + lane; i < end; i += 64) {
                    int sN = esrc[i];
                    float4 a4 = a_src4[sN];
                    float av[4] = {a4.x, a4.y, a4.z, a4.w};
                    #pragma unroll
                    for (int h = 0; h < 4; ++h) {
                        float e = av[h] + ad[h];
                        e = e > 0.f ? e : NEG_SLOPE * e;
                        float nm = fmaxf(m[h], e);
                        s[h] = s[h] * __expf(m[h] - nm) + __expf(e - nm);
                        m[h] = nm;
                    }
                }
                #pragma unroll
                for (int o = 32; o > 0; o >>= 1) {
                    #pragma unroll
                    for (int h = 0; h < 4; ++h) {
                        float om = __shfl_xor(m[h], o);
                        float os = __shfl_xor(s[h], o);
                        float nm = fmaxf(m[h], om);
                        s[h] = s[h] * __expf(m[h] - nm) + os * __expf(om - nm);
                        m[h] = nm;
                    }
                }
                float inv[4];
                #pragma unroll
                for (int h = 0; h < 4; ++h) inv[h] = 1.f / s[h];

                for (int c0 = beg; c0 < end; c0 += 64) {
                    int i = c0 + lane;
                    if (i < end) {
                        int sN = esrc[i];
                        float4 a4 = a_src4[sN];
                        float av[4] = {a4.x, a4.y, a4.z, a4.w};
                        uint4 pack;
                        #pragma unroll
                        for (int h = 0; h < 4; ++h) {
                            float e = av[h] + ad[h];
                            e = e > 0.f ? e : NEG_SLOPE * e;
                            __half2 a2h = __float2half2_rn(__expf(e - m[h]) * inv[h]);
                            ((unsigned*)&pack)[h] = *(unsigned*)&a2h;
                        }
                        *(uint4*)&lalh[wave][lane][0] = pack;
                        lsrc_s[wave][lane] = sN;
                    }
                    int cend = end - c0;
                    if (cend > 64) cend = 64;
                    GATHER(cend);
                }
            }
        }

        // stage this node's agg row to LDS (head-major within row)
        #pragma unroll
        for (int h = 0; h < 4; ++h)
            *(unsigned*)&aggl[ln][h * 128 + lane * 2] = *(unsigned*)&acc[h];
    }
    #undef GATHER
    __syncthreads();

    // ---- fused gemm2 epilogue: 8 waves = 2 row-groups x 4 col-groups ----
    const int q = lane >> 4;
    const int c16 = lane & 15;
    const int rg = wave & 1;
    const int cg = wave >> 1;
    const int row_l = rg * 16 + c16;

    f16x8 af[4];
    #pragma unroll
    for (int kc = 0; kc < 4; ++kc)
        af[kc] = *(const f16x8*)&aggl[row_l][cg * 128 + kc * 32 + q * 8];

    float pz[4] = {};
    #pragma unroll
    for (int t = 0; t < 4; ++t) {
        int col = cg * 64 + t * 16 + c16;
        f32x4 dacc = {0.f, 0.f, 0.f, 0.f};
        #pragma unroll
        for (int kc = 0; kc < 4; ++kc) {
            f16x8 b = *(const f16x8*)&W1T[(size_t)col * 128 + kc * 32 + q * 8];
            dacc = __builtin_amdgcn_mfma_f32_16x16x32_f16(af[kc], b, dacc, 0, 0, 0);
        }
        float bv = bias1[col];
        float wv = W2[col];
        #pragma unroll
        for (int reg = 0; reg < 4; ++reg) {
            float o = dacc[reg] + bv;
            o = o > 0.f ? o : __expf(o) - 1.f;
            pz[reg] = fmaf(o, wv, pz[reg]);
        }
    }
    #pragma unroll
    for (int o = 8; o > 0; o >>= 1) {
        #pragma unroll
        for (int reg = 0; reg < 4; ++reg) pz[reg] += __shfl_xor(pz[reg], o);
    }
    if (c16 == 0) {
        #pragma unroll
        for (int reg = 0; reg < 4; ++reg)
            zpart[cg][rg * 16 + q * 4 + reg] = pz[reg];
    }
    __syncthreads();
    if (threadIdx.x < 32) {
        int row = row0 + threadIdx.x;
        if (row < N)
            z[row] = zpart[0][threadIdx.x] + zpart[1][threadIdx.x] +
                     zpart[2][threadIdx.x] + zpart[3][threadIdx.x];
    }
}

// ---------------- Layer-2 aggregation: one wave per node ----------------
__global__ __launch_bounds__(256) void agg2_kernel(
    const float* __restrict__ z, const int* __restrict__ off,
    const int* __restrict__ esrc, const float* __restrict__ att_s2,
    const float* __restrict__ att_d2, const float* __restrict__ bias2,
    float* __restrict__ out, int N)
{
    int wave = threadIdx.x >> 6;
    int lane = threadIdx.x & 63;
    int n = blockIdx.x * 4 + wave;
    if (n >= N) return;
    float as2 = att_s2[0], ad2 = att_d2[0];
    int beg = off[n], end = off[n + 1];
    int deg = end - beg;
    float dstterm = z[n] * ad2;

    if (deg <= 64) {
        int i = beg + lane;
        bool valid = i < end;
        int sN = esrc[valid ? i : beg];
        float zv = z[sN];
        float e = zv * as2 + dstterm;
        e = e > 0.f ? e : NEG_SLOPE * e;
        float ev = valid ? e : -1e30f;
        float m = ev;
        #pragma unroll
        for (int o = 32; o > 0; o >>= 1) m = fmaxf(m, __shfl_xor(m, o));
        float at = valid ? __expf(ev - m) : 0.f;
        float s = at, wv = at * zv;
        #pragma unroll
        for (int o = 32; o > 0; o >>= 1) {
            s += __shfl_xor(s, o);
            wv += __shfl_xor(wv, o);
        }
        if (lane == 0) out[n] = wv / s + bias2[0];
    } else {
        float m = -1e30f, s = 0.f, wv = 0.f;
        for (int i = beg + lane; i < end; i += 64) {
            int sN = esrc[i];
            float zv = z[sN];
            float e = zv * as2 + dstterm;
            e = e > 0.f ? e : NEG_SLOPE * e;
            float nm = fmaxf(m, e);
            float c0 = __expf(m - nm), c1 = __expf(e - nm);
            s = s * c0 + c1;
            wv = wv * c0 + c1 * zv;
            m = nm;
        }
        #pragma unroll
        for (int o = 32; o > 0; o >>= 1) {
            float om = __shfl_xor(m, o), os = __shfl_xor(s, o), ow = __shfl_xor(wv, o);
            float nm = fmaxf(m, om);
            float c0 = __expf(m - nm), c1 = __expf(om - nm);
            s = s * c0 + os * c1;
            wv = wv * c0 + ow * c1;
            m = nm;
        }
        if (lane == 0) out[n] = wv / s + bias2[0];
    }
}

// ---------------- launch ----------------
extern "C" void kernel_launch(void* const* d_in, const int* in_sizes, int n_in,
                              void* d_out, int out_size, void* d_ws, size_t ws_size,
                              hipStream_t stream)
{
    const float* x        = (const float*)d_in[0];
    const int*   ei       = (const int*)d_in[1];
    const float* W1       = (const float*)d_in[2];
    const float* att_src1 = (const float*)d_in[3];
    const float* att_dst1 = (const float*)d_in[4];
    const float* bias1    = (const float*)d_in[5];
    const float* W2       = (const float*)d_in[6];
    const float* att_src2 = (const float*)d_in[7];
    const float* att_dst2 = (const float*)d_in[8];
    const float* bias2    = (const float*)d_in[9];
    float* out = (float*)d_out;

    int N = in_sizes[0] / INC;
    int E = in_sizes[1] / 2;
    int Etot = E + N;

    char* p = (char*)d_ws;
    auto alloc = [&](size_t bytes) {
        void* r = (void*)p;
        p += (bytes + 255) & ~(size_t)255;
        return r;
    };
    unsigned* x_h   = (unsigned*)alloc((size_t)N * 64 * 4);        // fp16 x, 12.8 MB
    _Float16* W1T   = (_Float16*)alloc((size_t)INC * F1 * 2);
    float* w1s    = (float*)alloc(4 * 128 * 4);
    float* w1d    = (float*)alloc(4 * 128 * 4);
    float* a_src1 = (float*)alloc((size_t)N * HEADS * 4);
    float* a_dst1 = (float*)alloc((size_t)N * HEADS * 4);
    float* z      = (float*)alloc((size_t)N * 4);
    int* deg    = (int*)alloc((size_t)N * 4);
    int* incl   = (int*)alloc((size_t)N * 4);
    int* off    = (int*)alloc((size_t)(N + 1) * 4);
    int* rank   = (int*)alloc((size_t)Etot * 4);
    int* bsum   = (int*)alloc(1024);
    int* esrc   = (int*)alloc((size_t)Etot * 4);

    hipMemsetAsync(deg, 0, (size_t)N * 4, stream);

    int nw1t = INC * F1 / 256;              // 128
    int egrid = (Etot + 255) / 256;
    prep_kernel<<<nw1t + egrid + 1, 256, 0, stream>>>(
        W1, W1T, att_src1, att_dst1, w1s, w1d, ei, deg, rank, E, Etot, nw1t);

    int nb = (N + 255) / 256;
    scan1_kernel<<<nb, 256, 0, stream>>>(deg, incl, bsum, N);

    int nb1 = (N + 1 + 255) / 256;
    scan3_kernel<<<nb1, 256, 0, stream>>>(deg, incl, bsum, off, N, Etot, nb);

    int nlog = (N + 3) / 4;
    mid_kernel<<<egrid + nlog, 256, 0, stream>>>(
        ei, rank, off, esrc, x, w1s, w1d, a_src1, a_dst1, x_h, N, E, Etot, egrid);

    int ngrid1 = (N + 31) / 32;
    aggx_kernel<<<ngrid1, 512, 0, stream>>>(
        x_h, a_src1, a_dst1, off, esrc, W1T, bias1, W2, z, N);

    int ngrid2 = (N + 3) / 4;
    agg2_kernel<<<ngrid2, 256, 0, stream>>>(z, off, esrc, att_src2, att_dst2, bias2, out, N);
}

// Round 15
// 175.843 us; speedup vs baseline: 1.3229x; 1.0730x over previous
//
#include <hip/hip_runtime.h>
#include <hip/hip_fp16.h>
#include <math.h>

#define INC 128
#define F1 256
#define HEADS 4
#define NEG_SLOPE 0.2f

typedef _Float16 f16x8 __attribute__((ext_vector_type(8)));
typedef float f32x4 __attribute__((ext_vector_type(4)));

// ---------------- prep: W1T + w1s/w1d projections + hist/rank ----------------
__global__ __launch_bounds__(256) void prep_kernel(
    const float* __restrict__ W1, _Float16* __restrict__ W1T,
    const float* __restrict__ att_s, const float* __restrict__ att_d,
    float* __restrict__ w1s, float* __restrict__ w1d,
    const int* __restrict__ ei, int* __restrict__ deg, int* __restrict__ rank,
    int E, int Etot, int nw1t)
{
    int b = blockIdx.x;
    if (b < nw1t) {
        int i = b * 256 + threadIdx.x;   // 32768 elements
        int k = i >> 8;
        int c = i & 255;
        W1T[c * 128 + k] = (_Float16)W1[i];
    } else if (b < nw1t + ((Etot + 255) >> 8)) {
        int e = (b - nw1t) * 256 + threadIdx.x;
        if (e < Etot) {
            int d = (e < E) ? ei[E + e] : (e - E);
            rank[e] = atomicAdd(&deg[d], 1);
        }
    } else {
        // w1s[h][k] = sum_c W1[k][h*64+c]*att_s[h*64+c]; same for w1d
        #pragma unroll
        for (int rep = 0; rep < 2; ++rep) {
            int idx = threadIdx.x + rep * 256;   // 512 outputs
            int h = idx >> 7;
            int k = idx & 127;
            float ss = 0.f, sd = 0.f;
            for (int c = 0; c < 64; ++c) {
                float w = W1[k * F1 + h * 64 + c];
                ss += w * att_s[h * 64 + c];
                sd += w * att_d[h * 64 + c];
            }
            w1s[h * 128 + k] = ss;
            w1d[h * 128 + k] = sd;
        }
    }
}

// ---------------- scan1 ----------------
__global__ __launch_bounds__(256) void scan1_kernel(
    const int* __restrict__ deg, int* __restrict__ incl,
    int* __restrict__ bsum, int N)
{
    __shared__ int tmp[256];
    int i = blockIdx.x * 256 + threadIdx.x;
    int v = (i < N) ? deg[i] : 0;
    tmp[threadIdx.x] = v;
    __syncthreads();
    for (int o = 1; o < 256; o <<= 1) {
        int add = (threadIdx.x >= o) ? tmp[threadIdx.x - o] : 0;
        __syncthreads();
        tmp[threadIdx.x] += add;
        __syncthreads();
    }
    if (i < N) incl[i] = tmp[threadIdx.x];
    if (threadIdx.x == 255) bsum[blockIdx.x] = tmp[255];
}

// ---------------- scan3 ----------------
__global__ __launch_bounds__(256) void scan3_kernel(
    const int* __restrict__ deg, const int* __restrict__ incl,
    const int* __restrict__ bsum, int* __restrict__ off,
    int N, int Etot, int nb)
{
    __shared__ int tmp[256];
    const int bid = blockIdx.x;
    const int t = threadIdx.x;
    tmp[t] = (t < bid && t < nb) ? bsum[t] : 0;
    __syncthreads();
    #pragma unroll
    for (int o = 128; o > 0; o >>= 1) {
        if (t < o) tmp[t] += tmp[t + o];
        __syncthreads();
    }
    int pre = tmp[0];
    int i = bid * 256 + t;
    if (i < N) {
        off[i] = incl[i] - deg[i] + pre;
    } else if (i == N) {
        off[N] = Etot;
    }
}

// ---------------- mid: fill (atomic-free) || logits a_src/a_dst + x->fp16 cast ----------------
__global__ __launch_bounds__(256) void mid_kernel(
    const int* __restrict__ ei, const int* __restrict__ rank,
    const int* __restrict__ off, int* __restrict__ esrc,
    const float* __restrict__ x, const float* __restrict__ w1s,
    const float* __restrict__ w1d, float* __restrict__ a_src,
    float* __restrict__ a_dst, unsigned* __restrict__ x_h,
    int N, int E, int Etot, int egrid)
{
    if ((int)blockIdx.x < egrid) {
        int e = blockIdx.x * 256 + threadIdx.x;
        if (e < Etot) {
            int s, d;
            if (e < E) { s = ei[e]; d = ei[E + e]; }
            else       { s = d = e - E; }
            esrc[off[d] + rank[e]] = s;
        }
        return;
    }
    int wave = threadIdx.x >> 6;
    int lane = threadIdx.x & 63;
    int n = (blockIdx.x - egrid) * 4 + wave;
    if (n >= N) return;
    float2 xv = *(const float2*)&x[(size_t)n * INC + lane * 2];
    __half2 xh = __floats2half2_rn(xv.x, xv.y);
    x_h[(size_t)n * 64 + lane] = *(unsigned*)&xh;
    float ps[4], pd[4];
    #pragma unroll
    for (int h = 0; h < 4; ++h) {
        float2 ws = *(const float2*)&w1s[h * 128 + lane * 2];
        float2 wd = *(const float2*)&w1d[h * 128 + lane * 2];
        ps[h] = xv.x * ws.x + xv.y * ws.y;
        pd[h] = xv.x * wd.x + xv.y * wd.y;
    }
    #pragma unroll
    for (int o = 32; o > 0; o >>= 1) {
        #pragma unroll
        for (int h = 0; h < 4; ++h) {
            ps[h] += __shfl_xor(ps[h], o);
            pd[h] += __shfl_xor(pd[h], o);
        }
    }
    if (lane == 0) {
        *(float4*)&a_src[n * HEADS] = make_float4(ps[0], ps[1], ps[2], ps[3]);
        *(float4*)&a_dst[n * HEADS] = make_float4(pd[0], pd[1], pd[2], pd[3]);
    }
}

// ---------------- aggx: per-head aggregate of x_fp16 (256B/edge gather) ----------------
// One WAVE per node. Lane: 2 channels. acc[h] half2 per head. (round-12 proven)
__global__ __launch_bounds__(256) void aggx_kernel(
    const unsigned* __restrict__ x_h, const float* __restrict__ a_src,
    const float* __restrict__ a_dst, const int* __restrict__ off,
    const int* __restrict__ esrc, __half* __restrict__ agg, int N)
{
    __shared__ unsigned lalh[4][64][4];  // [wave][edge][head] half2{a,a}
    __shared__ int lsrc_s[4][64];

    const int wave = threadIdx.x >> 6;
    const int lane = threadIdx.x & 63;
    const int n = blockIdx.x * 4 + wave;
    if (n >= N) return;

    const int beg = off[n], end = off[n + 1];
    const int deg = end - beg;
    const float4* a_src4 = (const float4*)a_src;
    float4 ad4 = *(const float4*)&a_dst[n * HEADS];
    float ad[4] = {ad4.x, ad4.y, ad4.z, ad4.w};

    __half2 acc[4];
    #pragma unroll
    for (int h = 0; h < 4; ++h) acc[h] = __float2half2_rn(0.f);

    #define GATHER(CNT)                                                          \
    {                                                                            \
        int j = 0;                                                               \
        for (; j + 4 <= (CNT); j += 4) {                                         \
            int s0 = lsrc_s[wave][j + 0];                                        \
            int s1 = lsrc_s[wave][j + 1];                                        \
            int s2 = lsrc_s[wave][j + 2];                                        \
            int s3 = lsrc_s[wave][j + 3];                                        \
            unsigned v0 = x_h[(size_t)s0 * 64 + lane];                           \
            unsigned v1 = x_h[(size_t)s1 * 64 + lane];                           \
            unsigned v2 = x_h[(size_t)s2 * 64 + lane];                           \
            unsigned v3 = x_h[(size_t)s3 * 64 + lane];                           \
            uint4 a0 = *(uint4*)&lalh[wave][j + 0][0];                           \
            uint4 a1 = *(uint4*)&lalh[wave][j + 1][0];                           \
            uint4 a2 = *(uint4*)&lalh[wave][j + 2][0];                           \
            uint4 a3 = *(uint4*)&lalh[wave][j + 3][0];                           \
            __half2 h0 = *(__half2*)&v0, h1v = *(__half2*)&v1;                   \
            __half2 h2v = *(__half2*)&v2, h3 = *(__half2*)&v3;                   \
            acc[0] = __hfma2(*(__half2*)&a0.x, h0, acc[0]);                      \
            acc[1] = __hfma2(*(__half2*)&a0.y, h0, acc[1]);                      \
            acc[2] = __hfma2(*(__half2*)&a0.z, h0, acc[2]);                      \
            acc[3] = __hfma2(*(__half2*)&a0.w, h0, acc[3]);                      \
            acc[0] = __hfma2(*(__half2*)&a1.x, h1v, acc[0]);                     \
            acc[1] = __hfma2(*(__half2*)&a1.y, h1v, acc[1]);                     \
            acc[2] = __hfma2(*(__half2*)&a1.z, h1v, acc[2]);                     \
            acc[3] = __hfma2(*(__half2*)&a1.w, h1v, acc[3]);                     \
            acc[0] = __hfma2(*(__half2*)&a2.x, h2v, acc[0]);                     \
            acc[1] = __hfma2(*(__half2*)&a2.y, h2v, acc[1]);                     \
            acc[2] = __hfma2(*(__half2*)&a2.z, h2v, acc[2]);                     \
            acc[3] = __hfma2(*(__half2*)&a2.w, h2v, acc[3]);                     \
            acc[0] = __hfma2(*(__half2*)&a3.x, h3, acc[0]);                      \
            acc[1] = __hfma2(*(__half2*)&a3.y, h3, acc[1]);                      \
            acc[2] = __hfma2(*(__half2*)&a3.z, h3, acc[2]);                      \
            acc[3] = __hfma2(*(__half2*)&a3.w, h3, acc[3]);                      \
        }                                                                        \
        for (; j < (CNT); ++j) {                                                 \
            int s0 = lsrc_s[wave][j];                                            \
            unsigned v0 = x_h[(size_t)s0 * 64 + lane];                           \
            uint4 a0 = *(uint4*)&lalh[wave][j][0];                               \
            __half2 h0 = *(__half2*)&v0;                                         \
            acc[0] = __hfma2(*(__half2*)&a0.x, h0, acc[0]);                      \
            acc[1] = __hfma2(*(__half2*)&a0.y, h0, acc[1]);                      \
            acc[2] = __hfma2(*(__half2*)&a0.z, h0, acc[2]);                      \
            acc[3] = __hfma2(*(__half2*)&a0.w, h0, acc[3]);                      \
        }                                                                        \
    }

    if (deg <= 64) {
        int i = beg + lane;
        bool valid = i < end;
        int sN = esrc[valid ? i : beg];
        float4 a4 = a_src4[sN];
        float av[4] = {a4.x, a4.y, a4.z, a4.w};
        float ev[4];
        #pragma unroll
        for (int h = 0; h < 4; ++h) {
            float e = av[h] + ad[h];
            e = e > 0.f ? e : NEG_SLOPE * e;
            ev[h] = valid ? e : -1e30f;
        }
        float m[4] = {ev[0], ev[1], ev[2], ev[3]};
        #pragma unroll
        for (int o = 32; o > 0; o >>= 1) {
            #pragma unroll
            for (int h = 0; h < 4; ++h) m[h] = fmaxf(m[h], __shfl_xor(m[h], o));
        }
        float at[4];
        #pragma unroll
        for (int h = 0; h < 4; ++h) at[h] = valid ? __expf(ev[h] - m[h]) : 0.f;
        float s[4] = {at[0], at[1], at[2], at[3]};
        #pragma unroll
        for (int o = 32; o > 0; o >>= 1) {
            #pragma unroll
            for (int h = 0; h < 4; ++h) s[h] += __shfl_xor(s[h], o);
        }
        uint4 pack;
        __half2 t0 = __float2half2_rn(at[0] / s[0]);
        __half2 t1 = __float2half2_rn(at[1] / s[1]);
        __half2 t2 = __float2half2_rn(at[2] / s[2]);
        __half2 t3 = __float2half2_rn(at[3] / s[3]);
        pack.x = *(unsigned*)&t0; pack.y = *(unsigned*)&t1;
        pack.z = *(unsigned*)&t2; pack.w = *(unsigned*)&t3;
        *(uint4*)&lalh[wave][lane][0] = pack;
        lsrc_s[wave][lane] = sN;

        GATHER(deg);
    } else {
        float m[4] = {-1e30f, -1e30f, -1e30f, -1e30f};
        float s[4] = {0.f, 0.f, 0.f, 0.f};
        for (int i = beg + lane; i < end; i += 64) {
            int sN = esrc[i];
            float4 a4 = a_src4[sN];
            float av[4] = {a4.x, a4.y, a4.z, a4.w};
            #pragma unroll
            for (int h = 0; h < 4; ++h) {
                float e = av[h] + ad[h];
                e = e > 0.f ? e : NEG_SLOPE * e;
                float nm = fmaxf(m[h], e);
                s[h] = s[h] * __expf(m[h] - nm) + __expf(e - nm);
                m[h] = nm;
            }
        }
        #pragma unroll
        for (int o = 32; o > 0; o >>= 1) {
            #pragma unroll
            for (int h = 0; h < 4; ++h) {
                float om = __shfl_xor(m[h], o);
                float os = __shfl_xor(s[h], o);
                float nm = fmaxf(m[h], om);
                s[h] = s[h] * __expf(m[h] - nm) + os * __expf(om - nm);
                m[h] = nm;
            }
        }
        float inv[4];
        #pragma unroll
        for (int h = 0; h < 4; ++h) inv[h] = 1.f / s[h];

        for (int c0 = beg; c0 < end; c0 += 64) {
            int i = c0 + lane;
            if (i < end) {
                int sN = esrc[i];
                float4 a4 = a_src4[sN];
                float av[4] = {a4.x, a4.y, a4.z, a4.w};
                uint4 pack;
                #pragma unroll
                for (int h = 0; h < 4; ++h) {
                    float e = av[h] + ad[h];
                    e = e > 0.f ? e : NEG_SLOPE * e;
                    __half2 a2h = __float2half2_rn(__expf(e - m[h]) * inv[h]);
                    ((unsigned*)&pack)[h] = *(unsigned*)&a2h;
                }
                *(uint4*)&lalh[wave][lane][0] = pack;
                lsrc_s[wave][lane] = sN;
            }
            int cend = end - c0;
            if (cend > 64) cend = 64;
            GATHER(cend);
        }
    }
    #undef GATHER

    // write agg[n][h][128] fp16
    #pragma unroll
    for (int h = 0; h < 4; ++h)
        *(unsigned*)&agg[(size_t)n * 512 + h * 128 + lane * 2] = *(unsigned*)&acc[h];
}

// ---------------- gemm2: out1 = blockdiag(agg @ W1) + bias -> ELU -> z = . W2 ----------------
// Block: 32 nodes, 4 waves. Wave w: rows (w&1)*16.., cols (w>>1)*128.. (round-12 proven)
__global__ __launch_bounds__(256, 4) void gemm2_kernel(
    const __half* __restrict__ agg, const _Float16* __restrict__ W1T,
    const float* __restrict__ bias1, const float* __restrict__ W2,
    float* __restrict__ z, int N)
{
    __shared__ __align__(16) _Float16 stg[32 * 520];
    __shared__ float zpart[2][32];

    const int tid = threadIdx.x;
    const int w = tid >> 6;
    const int lane = tid & 63;
    const int q = lane >> 4;
    const int c16 = lane & 15;
    const int row0 = blockIdx.x * 32;
    const int rg = w & 1;
    const int cg = w >> 1;

    #pragma unroll
    for (int it = 0; it < 8; ++it) {
        int flat = (tid + it * 256) * 8;    // half index in 32x512 tile
        int r = flat >> 9;
        int c = flat & 511;
        int row = row0 + r;
        uint4 v = (row < N) ? *(const uint4*)&agg[(size_t)row * 512 + c]
                            : make_uint4(0, 0, 0, 0);
        *(uint4*)&stg[r * 520 + c] = v;
    }
    __syncthreads();

    const int row_l = rg * 16 + c16;
    f16x8 af[2][4];
    #pragma unroll
    for (int hh = 0; hh < 2; ++hh) {
        int h = cg * 2 + hh;
        #pragma unroll
        for (int kc = 0; kc < 4; ++kc)
            af[hh][kc] = *(const f16x8*)&stg[row_l * 520 + h * 128 + kc * 32 + q * 8];
    }

    float pz[4] = {};
    #pragma unroll
    for (int hh = 0; hh < 2; ++hh) {
        #pragma unroll
        for (int t = 0; t < 4; ++t) {
            int col = cg * 128 + hh * 64 + t * 16 + c16;
            f32x4 acc = {0.f, 0.f, 0.f, 0.f};
            #pragma unroll
            for (int kc = 0; kc < 4; ++kc) {
                f16x8 b = *(const f16x8*)&W1T[(size_t)col * 128 + kc * 32 + q * 8];
                acc = __builtin_amdgcn_mfma_f32_16x16x32_f16(af[hh][kc], b, acc, 0, 0, 0);
            }
            float bv = bias1[col];
            float wv = W2[col];
            #pragma unroll
            for (int reg = 0; reg < 4; ++reg) {
                float o = acc[reg] + bv;
                o = o > 0.f ? o : __expf(o) - 1.f;
                pz[reg] = fmaf(o, wv, pz[reg]);
            }
        }
    }

    #pragma unroll
    for (int o = 8; o > 0; o >>= 1) {
        #pragma unroll
        for (int reg = 0; reg < 4; ++reg) pz[reg] += __shfl_xor(pz[reg], o);
    }
    if (c16 == 0) {
        #pragma unroll
        for (int reg = 0; reg < 4; ++reg)
            zpart[cg][rg * 16 + q * 4 + reg] = pz[reg];
    }
    __syncthreads();
    if (tid < 32) {
        int row = row0 + tid;
        if (row < N) z[row] = zpart[0][tid] + zpart[1][tid];
    }
}

// ---------------- Layer-2 aggregation: TWO nodes per wave (32 lanes each) ----------------
__global__ __launch_bounds__(256) void agg2_kernel(
    const float* __restrict__ z, const int* __restrict__ off,
    const int* __restrict__ esrc, const float* __restrict__ att_s2,
    const float* __restrict__ att_d2, const float* __restrict__ bias2,
    float* __restrict__ out, int N)
{
    int wave = threadIdx.x >> 6;
    int half = (threadIdx.x >> 5) & 1;
    int l32 = threadIdx.x & 31;
    int n = blockIdx.x * 8 + wave * 2 + half;
    if (n >= N) return;
    float as2 = att_s2[0], ad2 = att_d2[0];
    int beg = off[n], end = off[n + 1];
    int deg = end - beg;
    float dstterm = z[n] * ad2;

    if (deg <= 32) {
        int i = beg + l32;
        bool valid = i < end;
        int sN = esrc[valid ? i : beg];
        float zv = z[sN];
        float e = zv * as2 + dstterm;
        e = e > 0.f ? e : NEG_SLOPE * e;
        float ev = valid ? e : -1e30f;
        float m = ev;
        #pragma unroll
        for (int o = 16; o > 0; o >>= 1) m = fmaxf(m, __shfl_xor(m, o));
        float at = valid ? __expf(ev - m) : 0.f;
        float s = at, wv = at * zv;
        #pragma unroll
        for (int o = 16; o > 0; o >>= 1) {
            s += __shfl_xor(s, o);
            wv += __shfl_xor(wv, o);
        }
        if (l32 == 0) out[n] = wv / s + bias2[0];
    } else {
        float m = -1e30f, s = 0.f, wv = 0.f;
        for (int i = beg + l32; i < end; i += 32) {
            int sN = esrc[i];
            float zv = z[sN];
            float e = zv * as2 + dstterm;
            e = e > 0.f ? e : NEG_SLOPE * e;
            float nm = fmaxf(m, e);
            float c0 = __expf(m - nm), c1 = __expf(e - nm);
            s = s * c0 + c1;
            wv = wv * c0 + c1 * zv;
            m = nm;
        }
        #pragma unroll
        for (int o = 16; o > 0; o >>= 1) {
            float om = __shfl_xor(m, o), os = __shfl_xor(s, o), ow = __shfl_xor(wv, o);
            float nm = fmaxf(m, om);
            float c0 = __expf(m - nm), c1 = __expf(om - nm);
            s = s * c0 + os * c1;
            wv = wv * c0 + ow * c1;
            m = nm;
        }
        if (l32 == 0) out[n] = wv / s + bias2[0];
    }
}

// ---------------- launch ----------------
extern "C" void kernel_launch(void* const* d_in, const int* in_sizes, int n_in,
                              void* d_out, int out_size, void* d_ws, size_t ws_size,
                              hipStream_t stream)
{
    const float* x        = (const float*)d_in[0];
    const int*   ei       = (const int*)d_in[1];
    const float* W1       = (const float*)d_in[2];
    const float* att_src1 = (const float*)d_in[3];
    const float* att_dst1 = (const float*)d_in[4];
    const float* bias1    = (const float*)d_in[5];
    const float* W2       = (const float*)d_in[6];
    const float* att_src2 = (const float*)d_in[7];
    const float* att_dst2 = (const float*)d_in[8];
    const float* bias2    = (const float*)d_in[9];
    float* out = (float*)d_out;

    int N = in_sizes[0] / INC;
    int E = in_sizes[1] / 2;
    int Etot = E + N;

    char* p = (char*)d_ws;
    auto alloc = [&](size_t bytes) {
        void* r = (void*)p;
        p += (bytes + 255) & ~(size_t)255;
        return r;
    };
    unsigned* x_h   = (unsigned*)alloc((size_t)N * 64 * 4);        // fp16 x, 12.8 MB
    __half* agg     = (__half*)alloc((size_t)N * 512 * 2);         // 51.2 MB
    _Float16* W1T   = (_Float16*)alloc((size_t)INC * F1 * 2);
    float* w1s    = (float*)alloc(4 * 128 * 4);
    float* w1d    = (float*)alloc(4 * 128 * 4);
    float* a_src1 = (float*)alloc((size_t)N * HEADS * 4);
    float* a_dst1 = (float*)alloc((size_t)N * HEADS * 4);
    float* z      = (float*)alloc((size_t)N * 4);
    int* deg    = (int*)alloc((size_t)N * 4);
    int* incl   = (int*)alloc((size_t)N * 4);
    int* off    = (int*)alloc((size_t)(N + 1) * 4);
    int* rank   = (int*)alloc((size_t)Etot * 4);
    int* bsum   = (int*)alloc(1024);
    int* esrc   = (int*)alloc((size_t)Etot * 4);

    hipMemsetAsync(deg, 0, (size_t)N * 4, stream);

    int nw1t = INC * F1 / 256;              // 128
    int egrid = (Etot + 255) / 256;
    prep_kernel<<<nw1t + egrid + 1, 256, 0, stream>>>(
        W1, W1T, att_src1, att_dst1, w1s, w1d, ei, deg, rank, E, Etot, nw1t);

    int nb = (N + 255) / 256;
    scan1_kernel<<<nb, 256, 0, stream>>>(deg, incl, bsum, N);

    int nb1 = (N + 1 + 255) / 256;
    scan3_kernel<<<nb1, 256, 0, stream>>>(deg, incl, bsum, off, N, Etot, nb);

    int nlog = (N + 3) / 4;
    mid_kernel<<<egrid + nlog, 256, 0, stream>>>(
        ei, rank, off, esrc, x, w1s, w1d, a_src1, a_dst1, x_h, N, E, Etot, egrid);

    int ngrid1 = (N + 3) / 4;
    aggx_kernel<<<ngrid1, 256, 0, stream>>>(x_h, a_src1, a_dst1, off, esrc, agg, N);

    int ng2 = (N + 31) / 32;
    gemm2_kernel<<<ng2, 256, 0, stream>>>(agg, W1T, bias1, W2, z, N);

    int ngrid2 = (N + 7) / 8;
    agg2_kernel<<<ngrid2, 256, 0, stream>>>(z, off, esrc, att_src2, att_dst2, bias2, out, N);
}